// Round 1
// baseline (545.677 us; speedup 1.0000x reference)
//
#include <hip/hip_runtime.h>
#include <math.h>

#define NN   20000
#define EE   320000
#define ETOT 340000
#define FIN  128
#define HH   4
#define CC   64
#define HC   256
#define GG   64
#define BN_EPS 1e-5f

// ---------------- GEMM: C[M,Nc] = A[M,K] @ B[K,Nc], row-major fp32 ----------------
// BM=64, BN=64, BK=32, 256 threads, 4x4 outputs/thread.
__global__ __launch_bounds__(256) void gemm_kernel(const float* __restrict__ A,
        const float* __restrict__ B, float* __restrict__ Cmat,
        int M, int K, int Nc) {
    __shared__ float sA[64][33];
    __shared__ float sB[32][65];
    int t = threadIdx.x;
    int col0 = blockIdx.x * 64;
    int row0 = blockIdx.y * 64;
    int tx = t & 15, ty = t >> 4;
    float acc[4][4] = {};
    for (int k0 = 0; k0 < K; k0 += 32) {
        #pragma unroll
        for (int i = 0; i < 8; ++i) {
            int e = t + i * 256;
            int r = e >> 5, c = e & 31;
            int gr = row0 + r;
            sA[r][c] = (gr < M) ? A[gr * K + k0 + c] : 0.f;
        }
        #pragma unroll
        for (int i = 0; i < 8; ++i) {
            int e = t + i * 256;
            int r = e >> 6, c = e & 63;
            sB[r][c] = B[(k0 + r) * Nc + col0 + c];
        }
        __syncthreads();
        #pragma unroll
        for (int kk = 0; kk < 32; ++kk) {
            float a[4], b[4];
            #pragma unroll
            for (int j = 0; j < 4; ++j) a[j] = sA[ty * 4 + j][kk];
            #pragma unroll
            for (int j = 0; j < 4; ++j) b[j] = sB[kk][tx * 4 + j];
            #pragma unroll
            for (int j = 0; j < 4; ++j)
                #pragma unroll
                for (int l = 0; l < 4; ++l) acc[j][l] += a[j] * b[l];
        }
        __syncthreads();
    }
    #pragma unroll
    for (int j = 0; j < 4; ++j) {
        int gr = row0 + ty * 4 + j;
        if (gr < M) {
            #pragma unroll
            for (int l = 0; l < 4; ++l)
                Cmat[gr * Nc + col0 + tx * 4 + l] = acc[j][l];
        }
    }
}

// ---------------- attention logits: es[n,h] = <h1[n,h,:], a_src[h,:]>, same for ed --
__global__ __launch_bounds__(256) void att_kernel(const float* __restrict__ h,
        const float* __restrict__ a_src, const float* __restrict__ a_dst,
        float* __restrict__ es, float* __restrict__ ed) {
    int n = blockIdx.x;
    int t = threadIdx.x;          // 256 = 4 waves; wave == head
    int head = t >> 6, lane = t & 63;
    float v = h[n * HC + t];
    float s = v * a_src[head * CC + lane];
    float d = v * a_dst[head * CC + lane];
    #pragma unroll
    for (int off = 32; off; off >>= 1) {
        s += __shfl_down(s, off);
        d += __shfl_down(d, off);
    }
    if (lane == 0) { es[n * HH + head] = s; ed[n * HH + head] = d; }
}

// ---------------- CSR build ----------------
__global__ void count_kernel(const int* __restrict__ ei, int* __restrict__ deg) {
    int i = blockIdx.x * 256 + threadIdx.x;
    if (i >= ETOT) return;
    int d = (i < EE) ? ei[EE + i] : (i - EE);
    atomicAdd(&deg[d], 1);
}

__global__ __launch_bounds__(256) void scan1(const int* __restrict__ deg,
        int* __restrict__ off, int* __restrict__ part) {
    __shared__ int buf[256];
    int b = blockIdx.x, t = threadIdx.x;
    int i = b * 256 + t;
    int v = (i < NN) ? deg[i] : 0;
    buf[t] = v; __syncthreads();
    for (int s = 1; s < 256; s <<= 1) {
        int x = (t >= s) ? buf[t - s] : 0;
        __syncthreads();
        buf[t] += x;
        __syncthreads();
    }
    int incl = buf[t];
    if (i < NN) off[i] = incl - v;   // block-local exclusive
    if (t == 255) part[b] = incl;    // block total
}

__global__ __launch_bounds__(128) void scan2(int* __restrict__ part, int nb) {
    __shared__ int buf[128];
    int t = threadIdx.x;
    int v = (t < nb) ? part[t] : 0;
    buf[t] = v; __syncthreads();
    for (int s = 1; s < 128; s <<= 1) {
        int x = (t >= s) ? buf[t - s] : 0;
        __syncthreads();
        buf[t] += x;
        __syncthreads();
    }
    if (t < nb) part[t] = buf[t] - v;  // exclusive
}

__global__ __launch_bounds__(256) void scan3(int* __restrict__ off, const int* __restrict__ part) {
    int b = blockIdx.x, t = threadIdx.x;
    int i = b * 256 + t;
    if (i < NN) off[i] += part[b];
    if (i == 0) off[NN] = ETOT;
}

__global__ void fill_kernel(const int* __restrict__ ei, const int* __restrict__ off,
        int* __restrict__ cursor, int* __restrict__ csr_src) {
    int i = blockIdx.x * 256 + threadIdx.x;
    if (i >= ETOT) return;
    int s, d;
    if (i < EE) { s = ei[i]; d = ei[EE + i]; } else { s = i - EE; d = i - EE; }
    int pos = atomicAdd(&cursor[d], 1);
    csr_src[off[d] + pos] = s;
}

// ---------------- per-destination GAT aggregation (no float atomics) ----------------
// out[n,c] = 0.25 * sum_h ( sum_e w_eh * h[src_e,h,c] ) / (sum_e w_eh + 1e-16) + bias[c]
__global__ __launch_bounds__(64) void aggr_kernel(const float* __restrict__ h,
        const float* __restrict__ es, const float* __restrict__ edv,
        const int* __restrict__ off, const int* __restrict__ csr_src,
        const float* __restrict__ bias, float* __restrict__ out) {
    int n = blockIdx.x;
    int lane = threadIdx.x;
    float ed0 = edv[n * HH + 0], ed1 = edv[n * HH + 1];
    float ed2 = edv[n * HH + 2], ed3 = edv[n * HH + 3];
    float a0 = 0.f, a1 = 0.f, a2 = 0.f, a3 = 0.f;
    float s0 = 0.f, s1 = 0.f, s2 = 0.f, s3 = 0.f;
    int beg = off[n], end = off[n + 1];
    for (int j = beg; j < end; ++j) {
        int src = csr_src[j];
        const float* hrow = h + src * HC;
        const float* esr  = es + src * HH;
        float e0 = esr[0] + ed0; e0 = (e0 > 0.f) ? e0 : 0.2f * e0; float w0 = __expf(e0);
        float e1 = esr[1] + ed1; e1 = (e1 > 0.f) ? e1 : 0.2f * e1; float w1 = __expf(e1);
        float e2 = esr[2] + ed2; e2 = (e2 > 0.f) ? e2 : 0.2f * e2; float w2 = __expf(e2);
        float e3 = esr[3] + ed3; e3 = (e3 > 0.f) ? e3 : 0.2f * e3; float w3 = __expf(e3);
        a0 += w0 * hrow[0 * CC + lane]; s0 += w0;
        a1 += w1 * hrow[1 * CC + lane]; s1 += w1;
        a2 += w2 * hrow[2 * CC + lane]; s2 += w2;
        a3 += w3 * hrow[3 * CC + lane]; s3 += w3;
    }
    float val = 0.25f * (a0 / (s0 + 1e-16f) + a1 / (s1 + 1e-16f) +
                         a2 / (s2 + 1e-16f) + a3 / (s3 + 1e-16f)) + bias[lane];
    out[n * CC + lane] = val;
}

// ---------------- BN statistics: stats[0:64]=sum, stats[64:128]=sumsq ----------------
__global__ __launch_bounds__(256) void bnstat_kernel(const float* __restrict__ x,
        float* __restrict__ stats) {
    int t = threadIdx.x;
    int ch = t & 63, slice = t >> 6;
    float s = 0.f, q = 0.f;
    for (int n = blockIdx.x * 4 + slice; n < NN; n += gridDim.x * 4) {
        float v = x[n * CC + ch];
        s += v; q += v * v;
    }
    __shared__ float ls[4][64], lq[4][64];
    ls[slice][ch] = s; lq[slice][ch] = q;
    __syncthreads();
    if (slice == 0) {
        s = ls[0][ch] + ls[1][ch] + ls[2][ch] + ls[3][ch];
        q = lq[0][ch] + lq[1][ch] + lq[2][ch] + lq[3][ch];
        atomicAdd(&stats[ch], s);
        atomicAdd(&stats[CC + ch], q);
    }
}

__device__ __forceinline__ float gelu_exact(float v) {
    return 0.5f * v * (1.f + erff(v * 0.70710678118654752f));
}

// layer1: out = gelu(bn(gat) + skip + bskip)
__global__ __launch_bounds__(256) void bnapply1_kernel(const float* __restrict__ gout,
        const float* __restrict__ stats, const float* __restrict__ g,
        const float* __restrict__ be, const float* __restrict__ skip,
        const float* __restrict__ bskip, float* __restrict__ outm) {
    int i = blockIdx.x * 256 + threadIdx.x;
    if (i >= NN * CC) return;
    int ch = i & 63;
    float mu  = stats[ch] * (1.f / NN);
    float var = stats[CC + ch] * (1.f / NN) - mu * mu;
    float inv = rsqrtf(var + BN_EPS);
    float v = (gout[i] - mu) * inv * g[ch] + be[ch] + skip[i] + bskip[ch];
    outm[i] = gelu_exact(v);
}

// layer2: out = gelu(bn(gat) + resid)
__global__ __launch_bounds__(256) void bnapply2_kernel(const float* __restrict__ gout,
        const float* __restrict__ stats, const float* __restrict__ g,
        const float* __restrict__ be, const float* __restrict__ resid,
        float* __restrict__ outm) {
    int i = blockIdx.x * 256 + threadIdx.x;
    if (i >= NN * CC) return;
    int ch = i & 63;
    float mu  = stats[ch] * (1.f / NN);
    float var = stats[CC + ch] * (1.f / NN) - mu * mu;
    float inv = rsqrtf(var + BN_EPS);
    float v = (gout[i] - mu) * inv * g[ch] + be[ch] + resid[i];
    outm[i] = gelu_exact(v);
}

// ---------------- pooling ----------------
__global__ void gcnt_kernel(const int* __restrict__ bidx, int* __restrict__ gcnt) {
    int i = blockIdx.x * 256 + threadIdx.x;
    if (i < NN) atomicAdd(&gcnt[bidx[i]], 1);
}

__global__ __launch_bounds__(64) void pool_kernel(const float* __restrict__ h2,
        const int* __restrict__ gcnt, float* __restrict__ out) {
    __shared__ int cnts[GG];
    int g = blockIdx.x, lane = threadIdx.x;
    cnts[lane] = gcnt[lane];   // GG == blockDim == 64
    __syncthreads();
    int start = 0;
    for (int i = 0; i < g; ++i) start += cnts[i];
    int cnt = cnts[g];
    float s = 0.f;
    for (int n = start; n < start + cnt; ++n) s += h2[n * CC + lane];
    out[g * CC + lane] = s / (float)((cnt > 0) ? cnt : 1);
}

extern "C" void kernel_launch(void* const* d_in, const int* in_sizes, int n_in,
                              void* d_out, int out_size, void* d_ws, size_t ws_size,
                              hipStream_t stream) {
    const float* x      = (const float*)d_in[0];
    const float* W1     = (const float*)d_in[1];
    const float* a_src1 = (const float*)d_in[2];
    const float* a_dst1 = (const float*)d_in[3];
    const float* b1     = (const float*)d_in[4];
    const float* Wskip  = (const float*)d_in[5];
    const float* bskip  = (const float*)d_in[6];
    const float* g1     = (const float*)d_in[7];
    const float* be1    = (const float*)d_in[8];
    const float* W2     = (const float*)d_in[9];
    const float* a_src2 = (const float*)d_in[10];
    const float* a_dst2 = (const float*)d_in[11];
    const float* b2     = (const float*)d_in[12];
    const float* g2     = (const float*)d_in[13];
    const float* be2    = (const float*)d_in[14];
    const int*   ei     = (const int*)d_in[15];
    const int*   bidx   = (const int*)d_in[16];
    float* out = (float*)d_out;

    char* w = (char*)d_ws;
    size_t o = 0;
    auto alloc = [&](size_t bytes) -> void* {
        void* p = w + o;
        o = (o + bytes + 255) & ~(size_t)255;
        return p;
    };

    float* h1   = (float*)alloc((size_t)NN * HC * 4);  // projections (both layers)
    float* es   = (float*)alloc((size_t)NN * HH * 4);
    float* edv  = (float*)alloc((size_t)NN * HH * 4);
    float* skip = (float*)alloc((size_t)NN * CC * 4);  // layer1 skip; reused as h2 output
    float* gout = (float*)alloc((size_t)NN * CC * 4);  // gat output pre-BN (both layers)
    float* hmid = (float*)alloc((size_t)NN * CC * 4);  // layer1 output
    int* off    = (int*)alloc((size_t)(NN + 1) * 4);
    int* csr    = (int*)alloc((size_t)ETOT * 4);
    // ---- zero region (contiguous) ----
    char* zbase = w + o;
    int* deg    = (int*)alloc((size_t)NN * 4);
    int* cursor = (int*)alloc((size_t)NN * 4);
    int* gcnt   = (int*)alloc((size_t)GG * 4);
    int* part   = (int*)alloc(128 * 4);
    float* stats1 = (float*)alloc(128 * 4);
    float* stats2 = (float*)alloc(128 * 4);
    size_t zbytes = (size_t)((w + o) - zbase);
    float* h2 = skip;  // reuse

    hipMemsetAsync(zbase, 0, zbytes, stream);

    int ebk = (ETOT + 255) / 256;
    int nbk = (NN + 255) / 256;     // 79

    // CSR build (shared by both layers)
    count_kernel<<<ebk, 256, 0, stream>>>(ei, deg);
    scan1<<<nbk, 256, 0, stream>>>(deg, off, part);
    scan2<<<1, 128, 0, stream>>>(part, nbk);
    scan3<<<nbk, 256, 0, stream>>>(off, part);
    fill_kernel<<<ebk, 256, 0, stream>>>(ei, off, cursor, csr);

    dim3 gemm_blk(256);
    dim3 g_h(HC / 64, (NN + 63) / 64);
    dim3 g_s(CC / 64, (NN + 63) / 64);

    // ---- layer 1 ----
    gemm_kernel<<<g_h, gemm_blk, 0, stream>>>(x, W1, h1, NN, FIN, HC);
    gemm_kernel<<<g_s, gemm_blk, 0, stream>>>(x, Wskip, skip, NN, FIN, CC);
    att_kernel<<<NN, 256, 0, stream>>>(h1, a_src1, a_dst1, es, edv);
    aggr_kernel<<<NN, 64, 0, stream>>>(h1, es, edv, off, csr, b1, gout);
    bnstat_kernel<<<128, 256, 0, stream>>>(gout, stats1);
    bnapply1_kernel<<<(NN * CC + 255) / 256, 256, 0, stream>>>(
        gout, stats1, g1, be1, skip, bskip, hmid);

    // ---- layer 2 ----
    gemm_kernel<<<g_h, gemm_blk, 0, stream>>>(hmid, W2, h1, NN, CC, HC);
    att_kernel<<<NN, 256, 0, stream>>>(h1, a_src2, a_dst2, es, edv);
    aggr_kernel<<<NN, 64, 0, stream>>>(h1, es, edv, off, csr, b2, gout);
    bnstat_kernel<<<128, 256, 0, stream>>>(gout, stats2);
    bnapply2_kernel<<<(NN * CC + 255) / 256, 256, 0, stream>>>(
        gout, stats2, g2, be2, hmid, h2);

    // ---- pool ----
    gcnt_kernel<<<nbk, 256, 0, stream>>>(bidx, gcnt);
    pool_kernel<<<GG, 64, 0, stream>>>(h2, gcnt, out);
}

// Round 2
// 434.815 us; speedup vs baseline: 1.2550x; 1.2550x over previous
//
#include <hip/hip_runtime.h>
#include <math.h>

#define NN   20000
#define EE   320000
#define ETOT 340000
#define FIN  128
#define HH   4
#define CC   64
#define HC   256
#define GG   64
#define BN_EPS 1e-5f

// ---------------- GEMM: C[M,Nc] = A[M,K] @ B[K,Nc], row-major fp32 ----------------
// BM=64, BN=64, BK=32, 256 threads, 4x4 outputs/thread.
// A staged TRANSPOSED in LDS so inner loop is 2x ds_read_b128 + 16 v_fma per kk.
__global__ __launch_bounds__(256) void gemm_kernel(const float* __restrict__ A,
        const float* __restrict__ B, float* __restrict__ Cmat,
        int M, int K, int Nc) {
    __shared__ float sAT[32][68];   // [k][row]; stride 68*4=272B -> rows 16B aligned
    __shared__ float sB[32][68];    // [k][col]
    int t = threadIdx.x;
    int col0 = blockIdx.x * 64;
    int row0 = blockIdx.y * 64;
    int tx = t & 15, ty = t >> 4;   // thread covers rows ty*4..+3, cols tx*4..+3
    float acc[4][4] = {};
    for (int k0 = 0; k0 < K; k0 += 32) {
        // A tile: 64 rows x 32 k  (512 float4, 2 per thread), store transposed
        #pragma unroll
        for (int i = 0; i < 2; ++i) {
            int e = t + i * 256;
            int r = e >> 3, c4 = e & 7;
            int gr = row0 + r;
            float4 v = make_float4(0.f, 0.f, 0.f, 0.f);
            if (gr < M) v = *(const float4*)&A[(size_t)gr * K + k0 + c4 * 4];
            sAT[c4 * 4 + 0][r] = v.x;
            sAT[c4 * 4 + 1][r] = v.y;
            sAT[c4 * 4 + 2][r] = v.z;
            sAT[c4 * 4 + 3][r] = v.w;
        }
        // B tile: 32 k x 64 cols (512 float4, 2 per thread), direct layout
        #pragma unroll
        for (int i = 0; i < 2; ++i) {
            int e = t + i * 256;
            int r = e >> 4, c4 = e & 15;
            float4 v = *(const float4*)&B[(size_t)(k0 + r) * Nc + col0 + c4 * 4];
            *(float4*)&sB[r][c4 * 4] = v;
        }
        __syncthreads();
        #pragma unroll
        for (int kk = 0; kk < 32; ++kk) {
            float4 a = *(const float4*)&sAT[kk][ty * 4];
            float4 b = *(const float4*)&sB[kk][tx * 4];
            acc[0][0] += a.x * b.x; acc[0][1] += a.x * b.y; acc[0][2] += a.x * b.z; acc[0][3] += a.x * b.w;
            acc[1][0] += a.y * b.x; acc[1][1] += a.y * b.y; acc[1][2] += a.y * b.z; acc[1][3] += a.y * b.w;
            acc[2][0] += a.z * b.x; acc[2][1] += a.z * b.y; acc[2][2] += a.z * b.z; acc[2][3] += a.z * b.w;
            acc[3][0] += a.w * b.x; acc[3][1] += a.w * b.y; acc[3][2] += a.w * b.z; acc[3][3] += a.w * b.w;
        }
        __syncthreads();
    }
    #pragma unroll
    for (int j = 0; j < 4; ++j) {
        int gr = row0 + ty * 4 + j;
        if (gr < M) {
            float4 v = make_float4(acc[j][0], acc[j][1], acc[j][2], acc[j][3]);
            *(float4*)&Cmat[(size_t)gr * Nc + col0 + tx * 4] = v;
        }
    }
}

// ---------------- attention logits: es[n,h] = <h[n,h,:], a_src[h,:]> ----------------
__global__ __launch_bounds__(256) void att_kernel(const float* __restrict__ h,
        const float* __restrict__ a_src, const float* __restrict__ a_dst,
        float* __restrict__ es, float* __restrict__ ed) {
    int n = blockIdx.x;
    int t = threadIdx.x;          // 256 = 4 waves; wave == head
    int head = t >> 6, lane = t & 63;
    float v = h[n * HC + t];
    float s = v * a_src[head * CC + lane];
    float d = v * a_dst[head * CC + lane];
    #pragma unroll
    for (int off = 32; off; off >>= 1) {
        s += __shfl_down(s, off);
        d += __shfl_down(d, off);
    }
    if (lane == 0) { es[n * HH + head] = s; ed[n * HH + head] = d; }
}

// ---------------- CSR build ----------------
__global__ void count_kernel(const int* __restrict__ ei, int* __restrict__ deg) {
    int i = blockIdx.x * 256 + threadIdx.x;
    if (i >= ETOT) return;
    int d = (i < EE) ? ei[EE + i] : (i - EE);
    atomicAdd(&deg[d], 1);
}

__global__ __launch_bounds__(256) void scan1(const int* __restrict__ deg,
        int* __restrict__ off, int* __restrict__ part) {
    __shared__ int buf[256];
    int b = blockIdx.x, t = threadIdx.x;
    int i = b * 256 + t;
    int v = (i < NN) ? deg[i] : 0;
    buf[t] = v; __syncthreads();
    for (int s = 1; s < 256; s <<= 1) {
        int x = (t >= s) ? buf[t - s] : 0;
        __syncthreads();
        buf[t] += x;
        __syncthreads();
    }
    int incl = buf[t];
    if (i < NN) off[i] = incl - v;   // block-local exclusive
    if (t == 255) part[b] = incl;    // block total
}

__global__ __launch_bounds__(128) void scan2(int* __restrict__ part, int nb) {
    __shared__ int buf[128];
    int t = threadIdx.x;
    int v = (t < nb) ? part[t] : 0;
    buf[t] = v; __syncthreads();
    for (int s = 1; s < 128; s <<= 1) {
        int x = (t >= s) ? buf[t - s] : 0;
        __syncthreads();
        buf[t] += x;
        __syncthreads();
    }
    if (t < nb) part[t] = buf[t] - v;  // exclusive
}

__global__ __launch_bounds__(256) void scan3(int* __restrict__ off, const int* __restrict__ part) {
    int b = blockIdx.x, t = threadIdx.x;
    int i = b * 256 + t;
    if (i < NN) off[i] += part[b];
    if (i == 0) off[NN] = ETOT;
}

__global__ void fill_kernel(const int* __restrict__ ei, const int* __restrict__ off,
        int* __restrict__ cursor, int* __restrict__ csr_src) {
    int i = blockIdx.x * 256 + threadIdx.x;
    if (i >= ETOT) return;
    int s, d;
    if (i < EE) { s = ei[i]; d = ei[EE + i]; } else { s = i - EE; d = i - EE; }
    int pos = atomicAdd(&cursor[d], 1);
    csr_src[off[d] + pos] = s;
}

// ---------------- per-destination GAT aggregation (no float atomics) ----------------
// 256 threads = 4 waves; wave w handles node blockIdx.x*4+w; lane = channel.
__global__ __launch_bounds__(256) void aggr_kernel(const float* __restrict__ h,
        const float* __restrict__ es, const float* __restrict__ edv,
        const int* __restrict__ off, const int* __restrict__ csr_src,
        const float* __restrict__ bias, float* __restrict__ out) {
    int n = blockIdx.x * 4 + (threadIdx.x >> 6);
    if (n >= NN) return;
    int lane = threadIdx.x & 63;
    float4 edn = *(const float4*)&edv[n * HH];
    float a0 = 0.f, a1 = 0.f, a2 = 0.f, a3 = 0.f;
    float s0 = 0.f, s1 = 0.f, s2 = 0.f, s3 = 0.f;
    int beg = off[n], end = off[n + 1];
    for (int j = beg; j < end; ++j) {
        int src = csr_src[j];
        const float* hrow = h + src * HC;
        float4 esv = *(const float4*)&es[src * HH];
        float e0 = esv.x + edn.x; e0 = (e0 > 0.f) ? e0 : 0.2f * e0; float w0 = __expf(e0);
        float e1 = esv.y + edn.y; e1 = (e1 > 0.f) ? e1 : 0.2f * e1; float w1 = __expf(e1);
        float e2 = esv.z + edn.z; e2 = (e2 > 0.f) ? e2 : 0.2f * e2; float w2 = __expf(e2);
        float e3 = esv.w + edn.w; e3 = (e3 > 0.f) ? e3 : 0.2f * e3; float w3 = __expf(e3);
        a0 += w0 * hrow[0 * CC + lane]; s0 += w0;
        a1 += w1 * hrow[1 * CC + lane]; s1 += w1;
        a2 += w2 * hrow[2 * CC + lane]; s2 += w2;
        a3 += w3 * hrow[3 * CC + lane]; s3 += w3;
    }
    float val = 0.25f * (a0 / (s0 + 1e-16f) + a1 / (s1 + 1e-16f) +
                         a2 / (s2 + 1e-16f) + a3 / (s3 + 1e-16f)) + bias[lane];
    out[n * CC + lane] = val;
}

// ---------------- BN statistics: stats[0:64]=sum, stats[64:128]=sumsq ----------------
__global__ __launch_bounds__(256) void bnstat_kernel(const float* __restrict__ x,
        float* __restrict__ stats) {
    int t = threadIdx.x;
    int ch = t & 63, slice = t >> 6;
    float s = 0.f, q = 0.f;
    for (int n = blockIdx.x * 4 + slice; n < NN; n += gridDim.x * 4) {
        float v = x[n * CC + ch];
        s += v; q += v * v;
    }
    __shared__ float ls[4][64], lq[4][64];
    ls[slice][ch] = s; lq[slice][ch] = q;
    __syncthreads();
    if (slice == 0) {
        s = ls[0][ch] + ls[1][ch] + ls[2][ch] + ls[3][ch];
        q = lq[0][ch] + lq[1][ch] + lq[2][ch] + lq[3][ch];
        atomicAdd(&stats[ch], s);
        atomicAdd(&stats[CC + ch], q);
    }
}

__device__ __forceinline__ float gelu_exact(float v) {
    return 0.5f * v * (1.f + erff(v * 0.70710678118654752f));
}

// layer1: out = gelu(bn(gat) + skip + bskip)
__global__ __launch_bounds__(256) void bnapply1_kernel(const float* __restrict__ gout,
        const float* __restrict__ stats, const float* __restrict__ g,
        const float* __restrict__ be, const float* __restrict__ skip,
        const float* __restrict__ bskip, float* __restrict__ outm) {
    int i = blockIdx.x * 256 + threadIdx.x;
    if (i >= NN * CC) return;
    int ch = i & 63;
    float mu  = stats[ch] * (1.f / NN);
    float var = stats[CC + ch] * (1.f / NN) - mu * mu;
    float inv = rsqrtf(var + BN_EPS);
    float v = (gout[i] - mu) * inv * g[ch] + be[ch] + skip[i] + bskip[ch];
    outm[i] = gelu_exact(v);
}

// layer2: out = gelu(bn(gat) + resid)
__global__ __launch_bounds__(256) void bnapply2_kernel(const float* __restrict__ gout,
        const float* __restrict__ stats, const float* __restrict__ g,
        const float* __restrict__ be, const float* __restrict__ resid,
        float* __restrict__ outm) {
    int i = blockIdx.x * 256 + threadIdx.x;
    if (i >= NN * CC) return;
    int ch = i & 63;
    float mu  = stats[ch] * (1.f / NN);
    float var = stats[CC + ch] * (1.f / NN) - mu * mu;
    float inv = rsqrtf(var + BN_EPS);
    float v = (gout[i] - mu) * inv * g[ch] + be[ch] + resid[i];
    outm[i] = gelu_exact(v);
}

// ---------------- pooling (batch_idx sorted -> boundaries, no atomics) -------------
__global__ void gbound_kernel(const int* __restrict__ bidx, int* __restrict__ gstart) {
    int i = blockIdx.x * 256 + threadIdx.x;
    if (i >= NN) return;
    int cur = bidx[i];
    if (i == 0) {
        for (int g = 0; g <= cur; ++g) gstart[g] = 0;
    } else {
        int prev = bidx[i - 1];
        for (int g = prev + 1; g <= cur; ++g) gstart[g] = i;
    }
    if (i == NN - 1) {
        for (int g = cur + 1; g <= GG; ++g) gstart[g] = NN;
    }
}

__global__ __launch_bounds__(64) void pool_kernel(const float* __restrict__ h2,
        const int* __restrict__ gstart, float* __restrict__ out) {
    int g = blockIdx.x, lane = threadIdx.x;
    int start = gstart[g], end = gstart[g + 1];
    float s = 0.f;
    for (int n = start; n < end; ++n) s += h2[n * CC + lane];
    int cnt = end - start;
    out[g * CC + lane] = s / (float)((cnt > 0) ? cnt : 1);
}

extern "C" void kernel_launch(void* const* d_in, const int* in_sizes, int n_in,
                              void* d_out, int out_size, void* d_ws, size_t ws_size,
                              hipStream_t stream) {
    const float* x      = (const float*)d_in[0];
    const float* W1     = (const float*)d_in[1];
    const float* a_src1 = (const float*)d_in[2];
    const float* a_dst1 = (const float*)d_in[3];
    const float* b1     = (const float*)d_in[4];
    const float* Wskip  = (const float*)d_in[5];
    const float* bskip  = (const float*)d_in[6];
    const float* g1     = (const float*)d_in[7];
    const float* be1    = (const float*)d_in[8];
    const float* W2     = (const float*)d_in[9];
    const float* a_src2 = (const float*)d_in[10];
    const float* a_dst2 = (const float*)d_in[11];
    const float* b2     = (const float*)d_in[12];
    const float* g2     = (const float*)d_in[13];
    const float* be2    = (const float*)d_in[14];
    const int*   ei     = (const int*)d_in[15];
    const int*   bidx   = (const int*)d_in[16];
    float* out = (float*)d_out;

    char* w = (char*)d_ws;
    size_t o = 0;
    auto alloc = [&](size_t bytes) -> void* {
        void* p = w + o;
        o = (o + bytes + 255) & ~(size_t)255;
        return p;
    };

    float* h1   = (float*)alloc((size_t)NN * HC * 4);  // projections (both layers)
    float* es   = (float*)alloc((size_t)NN * HH * 4);
    float* edv  = (float*)alloc((size_t)NN * HH * 4);
    float* skip = (float*)alloc((size_t)NN * CC * 4);  // layer1 skip; reused as h2 output
    float* gout = (float*)alloc((size_t)NN * CC * 4);  // gat output pre-BN (both layers)
    float* hmid = (float*)alloc((size_t)NN * CC * 4);  // layer1 output
    int* off    = (int*)alloc((size_t)(NN + 1) * 4);
    int* csr    = (int*)alloc((size_t)ETOT * 4);
    int* gstart = (int*)alloc((size_t)(GG + 1) * 4);
    // ---- zero region (contiguous) ----
    char* zbase = w + o;
    int* deg    = (int*)alloc((size_t)NN * 4);
    int* cursor = (int*)alloc((size_t)NN * 4);
    int* part   = (int*)alloc(128 * 4);
    float* stats1 = (float*)alloc(128 * 4);
    float* stats2 = (float*)alloc(128 * 4);
    size_t zbytes = (size_t)((w + o) - zbase);
    float* h2 = skip;  // reuse

    hipMemsetAsync(zbase, 0, zbytes, stream);

    int ebk = (ETOT + 255) / 256;
    int nbk = (NN + 255) / 256;     // 79

    // CSR build (shared by both layers) + pool boundaries
    count_kernel<<<ebk, 256, 0, stream>>>(ei, deg);
    scan1<<<nbk, 256, 0, stream>>>(deg, off, part);
    scan2<<<1, 128, 0, stream>>>(part, nbk);
    scan3<<<nbk, 256, 0, stream>>>(off, part);
    fill_kernel<<<ebk, 256, 0, stream>>>(ei, off, cursor, csr);
    gbound_kernel<<<nbk, 256, 0, stream>>>(bidx, gstart);

    dim3 gemm_blk(256);
    dim3 g_h(HC / 64, (NN + 63) / 64);
    dim3 g_s(CC / 64, (NN + 63) / 64);
    int aggr_blk = (NN + 3) / 4;

    // ---- layer 1 ----
    gemm_kernel<<<g_h, gemm_blk, 0, stream>>>(x, W1, h1, NN, FIN, HC);
    gemm_kernel<<<g_s, gemm_blk, 0, stream>>>(x, Wskip, skip, NN, FIN, CC);
    att_kernel<<<NN, 256, 0, stream>>>(h1, a_src1, a_dst1, es, edv);
    aggr_kernel<<<aggr_blk, 256, 0, stream>>>(h1, es, edv, off, csr, b1, gout);
    bnstat_kernel<<<128, 256, 0, stream>>>(gout, stats1);
    bnapply1_kernel<<<(NN * CC + 255) / 256, 256, 0, stream>>>(
        gout, stats1, g1, be1, skip, bskip, hmid);

    // ---- layer 2 ----
    gemm_kernel<<<g_h, gemm_blk, 0, stream>>>(hmid, W2, h1, NN, CC, HC);
    att_kernel<<<NN, 256, 0, stream>>>(h1, a_src2, a_dst2, es, edv);
    aggr_kernel<<<aggr_blk, 256, 0, stream>>>(h1, es, edv, off, csr, b2, gout);
    bnstat_kernel<<<128, 256, 0, stream>>>(gout, stats2);
    bnapply2_kernel<<<(NN * CC + 255) / 256, 256, 0, stream>>>(
        gout, stats2, g2, be2, hmid, h2);

    // ---- pool ----
    pool_kernel<<<GG, 64, 0, stream>>>(h2, gstart, out);
}

// Round 3
// 350.714 us; speedup vs baseline: 1.5559x; 1.2398x over previous
//
#include <hip/hip_runtime.h>
#include <math.h>

#define NN   20000
#define EE   320000
#define ETOT 340000
#define FIN  128
#define HH   4
#define CC   64
#define HC   256
#define GG   64
#define BN_EPS 1e-5f

// ---------------- GEMM: C[M,Nc] = A[M,K] @ B[K,Nc], row-major fp32 ----------------
// BM=64, BN=64, BK=32, 256 threads, 4x4 outputs/thread.
// A staged TRANSPOSED in LDS so inner loop is 2x ds_read_b128 + 16 v_fma per kk.
__global__ __launch_bounds__(256) void gemm_kernel(const float* __restrict__ A,
        const float* __restrict__ B, float* __restrict__ Cmat,
        int M, int K, int Nc) {
    __shared__ float sAT[32][68];   // [k][row]; stride 68*4=272B -> rows 16B aligned
    __shared__ float sB[32][68];    // [k][col]
    int t = threadIdx.x;
    int col0 = blockIdx.x * 64;
    int row0 = blockIdx.y * 64;
    int tx = t & 15, ty = t >> 4;   // thread covers rows ty*4..+3, cols tx*4..+3
    float acc[4][4] = {};
    for (int k0 = 0; k0 < K; k0 += 32) {
        // A tile: 64 rows x 32 k  (512 float4, 2 per thread), store transposed
        #pragma unroll
        for (int i = 0; i < 2; ++i) {
            int e = t + i * 256;
            int r = e >> 3, c4 = e & 7;
            int gr = row0 + r;
            float4 v = make_float4(0.f, 0.f, 0.f, 0.f);
            if (gr < M) v = *(const float4*)&A[(size_t)gr * K + k0 + c4 * 4];
            sAT[c4 * 4 + 0][r] = v.x;
            sAT[c4 * 4 + 1][r] = v.y;
            sAT[c4 * 4 + 2][r] = v.z;
            sAT[c4 * 4 + 3][r] = v.w;
        }
        // B tile: 32 k x 64 cols (512 float4, 2 per thread), direct layout
        #pragma unroll
        for (int i = 0; i < 2; ++i) {
            int e = t + i * 256;
            int r = e >> 4, c4 = e & 15;
            float4 v = *(const float4*)&B[(size_t)(k0 + r) * Nc + col0 + c4 * 4];
            *(float4*)&sB[r][c4 * 4] = v;
        }
        __syncthreads();
        #pragma unroll
        for (int kk = 0; kk < 32; ++kk) {
            float4 a = *(const float4*)&sAT[kk][ty * 4];
            float4 b = *(const float4*)&sB[kk][tx * 4];
            acc[0][0] += a.x * b.x; acc[0][1] += a.x * b.y; acc[0][2] += a.x * b.z; acc[0][3] += a.x * b.w;
            acc[1][0] += a.y * b.x; acc[1][1] += a.y * b.y; acc[1][2] += a.y * b.z; acc[1][3] += a.y * b.w;
            acc[2][0] += a.z * b.x; acc[2][1] += a.z * b.y; acc[2][2] += a.z * b.z; acc[2][3] += a.z * b.w;
            acc[3][0] += a.w * b.x; acc[3][1] += a.w * b.y; acc[3][2] += a.w * b.z; acc[3][3] += a.w * b.w;
        }
        __syncthreads();
    }
    #pragma unroll
    for (int j = 0; j < 4; ++j) {
        int gr = row0 + ty * 4 + j;
        if (gr < M) {
            float4 v = make_float4(acc[j][0], acc[j][1], acc[j][2], acc[j][3]);
            *(float4*)&Cmat[(size_t)gr * Nc + col0 + tx * 4] = v;
        }
    }
}

// ---------------- attention logits: es[n,h] = <h[n,h,:], a_src[h,:]> ----------------
__global__ __launch_bounds__(256) void att_kernel(const float* __restrict__ h,
        const float* __restrict__ a_src, const float* __restrict__ a_dst,
        float* __restrict__ es, float* __restrict__ ed) {
    int n = blockIdx.x;
    int t = threadIdx.x;          // 256 = 4 waves; wave == head
    int head = t >> 6, lane = t & 63;
    float v = h[n * HC + t];
    float s = v * a_src[head * CC + lane];
    float d = v * a_dst[head * CC + lane];
    #pragma unroll
    for (int off = 32; off; off >>= 1) {
        s += __shfl_down(s, off);
        d += __shfl_down(d, off);
    }
    if (lane == 0) { es[n * HH + head] = s; ed[n * HH + head] = d; }
}

// ---------------- CSR build ----------------
__global__ void count_kernel(const int* __restrict__ ei, int* __restrict__ deg) {
    int i = blockIdx.x * 256 + threadIdx.x;
    if (i >= ETOT) return;
    int d = (i < EE) ? ei[EE + i] : (i - EE);
    atomicAdd(&deg[d], 1);
}

__global__ __launch_bounds__(256) void scan1(const int* __restrict__ deg,
        int* __restrict__ off, int* __restrict__ part) {
    __shared__ int buf[256];
    int b = blockIdx.x, t = threadIdx.x;
    int i = b * 256 + t;
    int v = (i < NN) ? deg[i] : 0;
    buf[t] = v; __syncthreads();
    for (int s = 1; s < 256; s <<= 1) {
        int x = (t >= s) ? buf[t - s] : 0;
        __syncthreads();
        buf[t] += x;
        __syncthreads();
    }
    int incl = buf[t];
    if (i < NN) off[i] = incl - v;   // block-local exclusive
    if (t == 255) part[b] = incl;    // block total
}

__global__ __launch_bounds__(128) void scan2(int* __restrict__ part, int nb) {
    __shared__ int buf[128];
    int t = threadIdx.x;
    int v = (t < nb) ? part[t] : 0;
    buf[t] = v; __syncthreads();
    for (int s = 1; s < 128; s <<= 1) {
        int x = (t >= s) ? buf[t - s] : 0;
        __syncthreads();
        buf[t] += x;
        __syncthreads();
    }
    if (t < nb) part[t] = buf[t] - v;  // exclusive
}

__global__ __launch_bounds__(256) void scan3(int* __restrict__ off, const int* __restrict__ part) {
    int b = blockIdx.x, t = threadIdx.x;
    int i = b * 256 + t;
    if (i < NN) off[i] += part[b];
    if (i == 0) off[NN] = ETOT;
}

__global__ void fill_kernel(const int* __restrict__ ei, const int* __restrict__ off,
        int* __restrict__ cursor, int* __restrict__ csr_src) {
    int i = blockIdx.x * 256 + threadIdx.x;
    if (i >= ETOT) return;
    int s, d;
    if (i < EE) { s = ei[i]; d = ei[EE + i]; } else { s = i - EE; d = i - EE; }
    int pos = atomicAdd(&cursor[d], 1);
    csr_src[off[d] + pos] = s;
}

// ---------------- per-destination GAT aggregation (no float atomics) ----------------
// 256 threads = 4 waves; wave w handles node blockIdx.x*4+w; lane = channel.
__global__ __launch_bounds__(256) void aggr_kernel(const float* __restrict__ h,
        const float* __restrict__ es, const float* __restrict__ edv,
        const int* __restrict__ off, const int* __restrict__ csr_src,
        const float* __restrict__ bias, float* __restrict__ out) {
    int n = blockIdx.x * 4 + (threadIdx.x >> 6);
    if (n >= NN) return;
    int lane = threadIdx.x & 63;
    float4 edn = *(const float4*)&edv[n * HH];
    float a0 = 0.f, a1 = 0.f, a2 = 0.f, a3 = 0.f;
    float s0 = 0.f, s1 = 0.f, s2 = 0.f, s3 = 0.f;
    int beg = off[n], end = off[n + 1];
    for (int j = beg; j < end; ++j) {
        int src = csr_src[j];
        const float* hrow = h + src * HC;
        float4 esv = *(const float4*)&es[src * HH];
        float e0 = esv.x + edn.x; e0 = (e0 > 0.f) ? e0 : 0.2f * e0; float w0 = __expf(e0);
        float e1 = esv.y + edn.y; e1 = (e1 > 0.f) ? e1 : 0.2f * e1; float w1 = __expf(e1);
        float e2 = esv.z + edn.z; e2 = (e2 > 0.f) ? e2 : 0.2f * e2; float w2 = __expf(e2);
        float e3 = esv.w + edn.w; e3 = (e3 > 0.f) ? e3 : 0.2f * e3; float w3 = __expf(e3);
        a0 += w0 * hrow[0 * CC + lane]; s0 += w0;
        a1 += w1 * hrow[1 * CC + lane]; s1 += w1;
        a2 += w2 * hrow[2 * CC + lane]; s2 += w2;
        a3 += w3 * hrow[3 * CC + lane]; s3 += w3;
    }
    float val = 0.25f * (a0 / (s0 + 1e-16f) + a1 / (s1 + 1e-16f) +
                         a2 / (s2 + 1e-16f) + a3 / (s3 + 1e-16f)) + bias[lane];
    out[n * CC + lane] = val;
}

// ---------------- BN statistics: stats[0:64]=sum, stats[64:128]=sumsq ----------------
__global__ __launch_bounds__(256) void bnstat_kernel(const float* __restrict__ x,
        float* __restrict__ stats) {
    int t = threadIdx.x;
    int ch = t & 63, slice = t >> 6;
    float s = 0.f, q = 0.f;
    for (int n = blockIdx.x * 4 + slice; n < NN; n += gridDim.x * 4) {
        float v = x[n * CC + ch];
        s += v; q += v * v;
    }
    __shared__ float ls[4][64], lq[4][64];
    ls[slice][ch] = s; lq[slice][ch] = q;
    __syncthreads();
    if (slice == 0) {
        s = ls[0][ch] + ls[1][ch] + ls[2][ch] + ls[3][ch];
        q = lq[0][ch] + lq[1][ch] + lq[2][ch] + lq[3][ch];
        atomicAdd(&stats[ch], s);
        atomicAdd(&stats[CC + ch], q);
    }
}

__device__ __forceinline__ float gelu_exact(float v) {
    return 0.5f * v * (1.f + erff(v * 0.70710678118654752f));
}

// layer1: out = gelu(bn(gat) + skip + bskip)
__global__ __launch_bounds__(256) void bnapply1_kernel(const float* __restrict__ gout,
        const float* __restrict__ stats, const float* __restrict__ g,
        const float* __restrict__ be, const float* __restrict__ skip,
        const float* __restrict__ bskip, float* __restrict__ outm) {
    int i = blockIdx.x * 256 + threadIdx.x;
    if (i >= NN * CC) return;
    int ch = i & 63;
    float mu  = stats[ch] * (1.f / NN);
    float var = stats[CC + ch] * (1.f / NN) - mu * mu;
    float inv = rsqrtf(var + BN_EPS);
    float v = (gout[i] - mu) * inv * g[ch] + be[ch] + skip[i] + bskip[ch];
    outm[i] = gelu_exact(v);
}

// layer2: out = gelu(bn(gat) + resid)
__global__ __launch_bounds__(256) void bnapply2_kernel(const float* __restrict__ gout,
        const float* __restrict__ stats, const float* __restrict__ g,
        const float* __restrict__ be, const float* __restrict__ resid,
        float* __restrict__ outm) {
    int i = blockIdx.x * 256 + threadIdx.x;
    if (i >= NN * CC) return;
    int ch = i & 63;
    float mu  = stats[ch] * (1.f / NN);
    float var = stats[CC + ch] * (1.f / NN) - mu * mu;
    float inv = rsqrtf(var + BN_EPS);
    float v = (gout[i] - mu) * inv * g[ch] + be[ch] + resid[i];
    outm[i] = gelu_exact(v);
}

// ---------------- pooling (batch_idx sorted -> boundaries, no atomics) -------------
__global__ void gbound_kernel(const int* __restrict__ bidx, int* __restrict__ gstart) {
    int i = blockIdx.x * 256 + threadIdx.x;
    if (i >= NN) return;
    int cur = bidx[i];
    if (i == 0) {
        for (int g = 0; g <= cur; ++g) gstart[g] = 0;
    } else {
        int prev = bidx[i - 1];
        for (int g = prev + 1; g <= cur; ++g) gstart[g] = i;
    }
    if (i == NN - 1) {
        for (int g = cur + 1; g <= GG; ++g) gstart[g] = NN;
    }
}

// One 1024-thread block per graph; 64 node-slices in flight; float4 channels.
__global__ __launch_bounds__(1024) void pool_kernel(const float* __restrict__ h2,
        const int* __restrict__ gstart, float* __restrict__ out) {
    __shared__ float4 sdata[64][17];
    int g = blockIdx.x;
    int t = threadIdx.x;
    int c4 = t & 15;        // which float4 of the 64-float row
    int slice = t >> 4;     // 0..63 node slice
    int start = gstart[g], end = gstart[g + 1];
    float4 acc = make_float4(0.f, 0.f, 0.f, 0.f);
    for (int n = start + slice; n < end; n += 64) {
        float4 v = *(const float4*)&h2[(size_t)n * CC + c4 * 4];
        acc.x += v.x; acc.y += v.y; acc.z += v.z; acc.w += v.w;
    }
    sdata[slice][c4] = acc;
    __syncthreads();
    #pragma unroll
    for (int s = 32; s >= 1; s >>= 1) {
        if (slice < s) {
            float4 o = sdata[slice + s][c4];
            acc.x += o.x; acc.y += o.y; acc.z += o.z; acc.w += o.w;
            sdata[slice][c4] = acc;
        }
        __syncthreads();
    }
    if (slice == 0) {
        int cnt = end - start;
        float inv = 1.f / (float)((cnt > 0) ? cnt : 1);
        float4 r = make_float4(acc.x * inv, acc.y * inv, acc.z * inv, acc.w * inv);
        *(float4*)&out[g * CC + c4 * 4] = r;
    }
}

extern "C" void kernel_launch(void* const* d_in, const int* in_sizes, int n_in,
                              void* d_out, int out_size, void* d_ws, size_t ws_size,
                              hipStream_t stream) {
    const float* x      = (const float*)d_in[0];
    const float* W1     = (const float*)d_in[1];
    const float* a_src1 = (const float*)d_in[2];
    const float* a_dst1 = (const float*)d_in[3];
    const float* b1     = (const float*)d_in[4];
    const float* Wskip  = (const float*)d_in[5];
    const float* bskip  = (const float*)d_in[6];
    const float* g1     = (const float*)d_in[7];
    const float* be1    = (const float*)d_in[8];
    const float* W2     = (const float*)d_in[9];
    const float* a_src2 = (const float*)d_in[10];
    const float* a_dst2 = (const float*)d_in[11];
    const float* b2     = (const float*)d_in[12];
    const float* g2     = (const float*)d_in[13];
    const float* be2    = (const float*)d_in[14];
    const int*   ei     = (const int*)d_in[15];
    const int*   bidx   = (const int*)d_in[16];
    float* out = (float*)d_out;

    char* w = (char*)d_ws;
    size_t o = 0;
    auto alloc = [&](size_t bytes) -> void* {
        void* p = w + o;
        o = (o + bytes + 255) & ~(size_t)255;
        return p;
    };

    float* h1   = (float*)alloc((size_t)NN * HC * 4);  // projections (both layers)
    float* es   = (float*)alloc((size_t)NN * HH * 4);
    float* edv  = (float*)alloc((size_t)NN * HH * 4);
    float* skip = (float*)alloc((size_t)NN * CC * 4);  // layer1 skip; reused as h2 output
    float* gout = (float*)alloc((size_t)NN * CC * 4);  // gat output pre-BN (both layers)
    float* hmid = (float*)alloc((size_t)NN * CC * 4);  // layer1 output
    int* off    = (int*)alloc((size_t)(NN + 1) * 4);
    int* csr    = (int*)alloc((size_t)ETOT * 4);
    int* gstart = (int*)alloc((size_t)(GG + 1) * 4);
    // ---- zero region (contiguous) ----
    char* zbase = w + o;
    int* deg    = (int*)alloc((size_t)NN * 4);
    int* cursor = (int*)alloc((size_t)NN * 4);
    int* part   = (int*)alloc(128 * 4);
    float* stats1 = (float*)alloc(128 * 4);
    float* stats2 = (float*)alloc(128 * 4);
    size_t zbytes = (size_t)((w + o) - zbase);
    float* h2 = skip;  // reuse

    hipMemsetAsync(zbase, 0, zbytes, stream);

    int ebk = (ETOT + 255) / 256;
    int nbk = (NN + 255) / 256;     // 79

    // CSR build (shared by both layers) + pool boundaries
    count_kernel<<<ebk, 256, 0, stream>>>(ei, deg);
    scan1<<<nbk, 256, 0, stream>>>(deg, off, part);
    scan2<<<1, 128, 0, stream>>>(part, nbk);
    scan3<<<nbk, 256, 0, stream>>>(off, part);
    fill_kernel<<<ebk, 256, 0, stream>>>(ei, off, cursor, csr);
    gbound_kernel<<<nbk, 256, 0, stream>>>(bidx, gstart);

    dim3 gemm_blk(256);
    dim3 g_h(HC / 64, (NN + 63) / 64);
    dim3 g_s(CC / 64, (NN + 63) / 64);
    int aggr_blk = (NN + 3) / 4;

    // ---- layer 1 ----
    gemm_kernel<<<g_h, gemm_blk, 0, stream>>>(x, W1, h1, NN, FIN, HC);
    gemm_kernel<<<g_s, gemm_blk, 0, stream>>>(x, Wskip, skip, NN, FIN, CC);
    att_kernel<<<NN, 256, 0, stream>>>(h1, a_src1, a_dst1, es, edv);
    aggr_kernel<<<aggr_blk, 256, 0, stream>>>(h1, es, edv, off, csr, b1, gout);
    bnstat_kernel<<<128, 256, 0, stream>>>(gout, stats1);
    bnapply1_kernel<<<(NN * CC + 255) / 256, 256, 0, stream>>>(
        gout, stats1, g1, be1, skip, bskip, hmid);

    // ---- layer 2 ----
    gemm_kernel<<<g_h, gemm_blk, 0, stream>>>(hmid, W2, h1, NN, CC, HC);
    att_kernel<<<NN, 256, 0, stream>>>(h1, a_src2, a_dst2, es, edv);
    aggr_kernel<<<aggr_blk, 256, 0, stream>>>(h1, es, edv, off, csr, b2, gout);
    bnstat_kernel<<<128, 256, 0, stream>>>(gout, stats2);
    bnapply2_kernel<<<(NN * CC + 255) / 256, 256, 0, stream>>>(
        gout, stats2, g2, be2, hmid, h2);

    // ---- pool ----
    pool_kernel<<<GG, 1024, 0, stream>>>(h2, gstart, out);
}